// Round 2
// baseline (260.238 us; speedup 1.0000x reference)
//
#include <hip/hip_runtime.h>
#include <hip/hip_fp16.h>

// Multi-Scale Deformable Attention:
//   cvt value fp32->fp16 (d_ws) + Wout^T fp16 (ws tail) -> gather (fp16)
//   -> MFMA fp16 output GEMM (in-place on d_out)
// BS=2, NQ=32768, C=128, NH=1, NL=2, NP=8, NV=40960
// level0 = 128x256 (start 0), level1 = 64x128 (start 32768)

#define QB 32  // queries per block (gather kernel)

struct __align__(8) h2x2 { __half2 a, b; };   // 4 fp16 channels (8 B)

typedef _Float16 f16x8 __attribute__((ext_vector_type(8)));
typedef _Float16 f16x4 __attribute__((ext_vector_type(4)));
typedef float    f32x4 __attribute__((ext_vector_type(4)));

// ---- value fp32 -> fp16 conversion ----
__global__ __launch_bounds__(256) void cvt_value_f16_kernel(
    const float4* __restrict__ in, h2x2* __restrict__ out, int n4)
{
    const int i = blockIdx.x * 256 + threadIdx.x;
    if (i < n4) {
        const float4 f = in[i];
        h2x2 h;
        h.a = __floats2half2_rn(f.x, f.y);
        h.b = __floats2half2_rn(f.z, f.w);
        out[i] = h;
    }
}

// ---- Wout (fp32 [k][n]) -> wTg (fp16 [n][k]) one-block transpose ----
__global__ __launch_bounds__(256) void wout_transpose_kernel(
    const float* __restrict__ Wout, _Float16* __restrict__ wTg)
{
    __shared__ float t[128 * 129];
    const int tid = threadIdx.x;
    #pragma unroll
    for (int i = 0; i < 16; ++i) {
        const int f  = tid + i * 256;     // 0..4095 float4s
        const int k  = f >> 5;
        const int c4 = f & 31;
        const float4 v = ((const float4*)Wout)[k * 32 + c4];
        t[k * 129 + c4 * 4 + 0] = v.x;
        t[k * 129 + c4 * 4 + 1] = v.y;
        t[k * 129 + c4 * 4 + 2] = v.z;
        t[k * 129 + c4 * 4 + 3] = v.w;
    }
    __syncthreads();
    #pragma unroll
    for (int i = 0; i < 64; ++i) {
        const int f = tid + i * 256;      // 0..16383
        const int n = f >> 7;
        const int k = f & 127;
        wTg[n * 128 + k] = (_Float16)t[k * 129 + n];
    }
}

// ---------- shared prologue --------------------------------------------------
// One thread owns one (query-pair, point): computes x/y offset dots + attn
// logit dot (6 x 128-length dot products), softmax over its 16-lane group in
// registers, and writes its own two table entries. No coords/aws LDS buffers:
// total LDS = 16 KB (q_tile reused as tab).
// NOTE: gather uses __launch_bounds__(256, 4) NOT (256, 8): the 64-VGPR cap
// from min-waves=8 made the scheduler serialize the 16-deep load batch
// (VGPR 48->32, VALUBusy 47->39, dur 106->128 us). At 48 VGPR (<=64) the HW
// already schedules 8 waves/SIMD; LDS 16 KB allows 10 blocks -> 8 blocks/CU.
#define MSDA_PROLOGUE                                                          \
    float* q_tile = (float*)smem_u;                                            \
    int4*  tab    = (int4*)smem_u;                                             \
    const int tid = threadIdx.x;                                               \
    const int r0  = blockIdx.x * QB;                                           \
    {                                                                          \
        const float4* src = (const float4*)query + (size_t)r0 * 32;            \
        float4* dst = (float4*)q_tile;                                         \
        _Pragma("unroll")                                                      \
        for (int i = 0; i < 4; ++i)                                            \
            dst[tid + i * 256] = src[tid + i * 256];                           \
    }                                                                          \
    __syncthreads();                                                           \
    {                                                                          \
        const int qg  = tid >> 4;            /* 0..15: queries qg*2+k */       \
        const int p   = tid & 15;            /* global point 0..15 */          \
        const int l   = p >> 3;                                                \
        const int pin = p & 7;                                                 \
        const int jx  = l * 16 + pin * 2;    /* x column in Woff (32 cols) */  \
        float sx[2] = {0.f, 0.f}, sy[2] = {0.f, 0.f}, sa[2] = {0.f, 0.f};      \
        for (int c4 = 0; c4 < 32; ++c4) {                                      \
            float2 wxy[4]; float wat[4];                                       \
            _Pragma("unroll")                                                  \
            for (int r = 0; r < 4; ++r) {                                      \
                wxy[r] = *(const float2*)&Woff[(c4 * 4 + r) * 32 + jx];        \
                wat[r] = Wattn[(c4 * 4 + r) * 16 + p];                         \
            }                                                                  \
            _Pragma("unroll")                                                  \
            for (int k = 0; k < 2; ++k) {                                      \
                const float4 q4 = *(const float4*)&q_tile[(qg * 2 + k) * 128 + c4 * 4]; \
                sx[k] += q4.x * wxy[0].x + q4.y * wxy[1].x                     \
                       + q4.z * wxy[2].x + q4.w * wxy[3].x;                    \
                sy[k] += q4.x * wxy[0].y + q4.y * wxy[1].y                     \
                       + q4.z * wxy[2].y + q4.w * wxy[3].y;                    \
                sa[k] += q4.x * wat[0] + q4.y * wat[1]                         \
                       + q4.z * wat[2] + q4.w * wat[3];                        \
            }                                                                  \
        }                                                                      \
        const float Wf = l ? 128.f : 256.f;                                    \
        const float Hf = l ? 64.f : 128.f;                                     \
        const float box = boff[jx], boy = boff[jx + 1];                        \
        const float ba  = battn[p];                                            \
        float xx[2], yy[2], lg[2];                                             \
        _Pragma("unroll")                                                      \
        for (int k = 0; k < 2; ++k) {                                          \
            const int row = r0 + qg * 2 + k;                                   \
            xx[k] = qloc[row * 4 + l * 2 + 0] * Wf + (sx[k] + box) - 0.5f;     \
            yy[k] = qloc[row * 4 + l * 2 + 1] * Hf + (sy[k] + boy) - 0.5f;     \
            lg[k] = sa[k] + ba;                                                \
        }                                                                      \
        /* softmax over the 16 lanes of this contiguous lane group */          \
        float m0 = lg[0], m1 = lg[1];                                          \
        _Pragma("unroll")                                                      \
        for (int s_ = 1; s_ < 16; s_ <<= 1) {                                  \
            m0 = fmaxf(m0, __shfl_xor(m0, s_, 64));                            \
            m1 = fmaxf(m1, __shfl_xor(m1, s_, 64));                            \
        }                                                                      \
        float ex0 = __expf(lg[0] - m0), ex1 = __expf(lg[1] - m1);              \
        float sm0 = ex0, sm1 = ex1;                                            \
        _Pragma("unroll")                                                      \
        for (int s_ = 1; s_ < 16; s_ <<= 1) {                                  \
            sm0 += __shfl_xor(sm0, s_, 64);                                    \
            sm1 += __shfl_xor(sm1, s_, 64);                                    \
        }                                                                      \
        const float wgt_[2] = {ex0 / sm0, ex1 / sm1};                          \
        __syncthreads();   /* q_tile reads done; safe to overwrite with tab */ \
        const int Hi = l ? 64 : 128;                                           \
        const int Wi = l ? 128 : 256;                                          \
        const int S  = l ? 32768 : 0;                                          \
        _Pragma("unroll")                                                      \
        for (int k = 0; k < 2; ++k) {                                          \
            const int q = qg * 2 + k;                                          \
            const float x = xx[k], y = yy[k];                                  \
            const float wgt = wgt_[k];                                         \
            const float xf = floorf(x), yf = floorf(y);                        \
            const float lx = x - xf, ly = y - yf;                              \
            const int x0 = (int)xf, y0 = (int)yf;                              \
            const int x1 = x0 + 1, y1 = y0 + 1;                                \
            const float hx = 1.f - lx, hy = 1.f - ly;                          \
            float w00 = wgt * hx * hy;                                         \
            float w10 = wgt * lx * hy;                                         \
            float w01 = wgt * hx * ly;                                         \
            float w11 = wgt * lx * ly;                                         \
            if (x0 < 0 || x0 >= Wi) { w00 = 0.f; w01 = 0.f; }                  \
            if (x1 < 0 || x1 >= Wi) { w10 = 0.f; w11 = 0.f; }                  \
            if (y0 < 0 || y0 >= Hi) { w00 = 0.f; w10 = 0.f; }                  \
            if (y1 < 0 || y1 >= Hi) { w01 = 0.f; w11 = 0.f; }                  \
            const int cx0 = min(max(x0, 0), Wi - 1);                           \
            const int cx1 = min(max(x1, 0), Wi - 1);                           \
            const int cy0 = min(max(y0, 0), Hi - 1);                           \
            const int cy1 = min(max(y1, 0), Hi - 1);                           \
            int4 e0i, e1i;                                                     \
            e0i.x = __float_as_int(w00); e0i.y = __float_as_int(w01);          \
            e0i.z = (S + cy0 * Wi + cx0) * 32; e0i.w = (S + cy1 * Wi + cx0) * 32; \
            e1i.x = __float_as_int(w10); e1i.y = __float_as_int(w11);          \
            e1i.z = (S + cy0 * Wi + cx1) * 32; e1i.w = (S + cy1 * Wi + cx1) * 32; \
            const int e_ = q * 16 + p;                                         \
            tab[e_ * 2]     = e0i;                                             \
            tab[e_ * 2 + 1] = e1i;                                             \
        }                                                                      \
    }                                                                          \
    __syncthreads();

// ---- gather, fp16 value path ----
__global__ __launch_bounds__(256, 4) void msda_gather_f16_kernel(
    const float* __restrict__ query,
    const h2x2*  __restrict__ value_h,
    const float* __restrict__ qloc,
    const float* __restrict__ Woff,
    const float* __restrict__ boff,
    const float* __restrict__ Wattn,
    const float* __restrict__ battn,
    float* __restrict__ acc_out)
{
    __shared__ __align__(16) char smem_u[QB * 128 * 4];   // 16 KB: q_tile / tab
    MSDA_PROLOGUE

    {
        const int wv   = tid >> 6;
        const int lane = tid & 63;
        const int half = lane >> 5;
        const int cl   = lane & 31;
        const h2x2* vb = value_h + (size_t)(blockIdx.x >> 10) * (40960 * 32);
        float4* og = (float4*)acc_out;

        #pragma unroll 1
        for (int i = 0; i < 8; ++i) {
            const int q = wv * 8 + i;
            float ax = 0.f, ay = 0.f, az = 0.f, aw4 = 0.f;

            #pragma unroll 1
            for (int p0 = 0; p0 < 16; p0 += 8) {
                float wa[8], wb[8];
                int   oa[8], ob[8];
                #pragma unroll
                for (int pi = 0; pi < 8; ++pi) {
                    const int4 t = tab[((q * 16 + p0 + pi) << 1) + half];
                    wa[pi] = __int_as_float(t.x);
                    wb[pi] = __int_as_float(t.y);
                    oa[pi] = t.z + cl;
                    ob[pi] = t.w + cl;
                }
                h2x2 vA[8], vB[8];
                #pragma unroll
                for (int pi = 0; pi < 8; ++pi) {
                    vA[pi] = vb[oa[pi]];
                    vB[pi] = vb[ob[pi]];
                }
                #pragma unroll
                for (int pi = 0; pi < 8; ++pi) {
                    ax  += wa[pi] * __low2float(vA[pi].a);
                    ay  += wa[pi] * __high2float(vA[pi].a);
                    az  += wa[pi] * __low2float(vA[pi].b);
                    aw4 += wa[pi] * __high2float(vA[pi].b);
                    ax  += wb[pi] * __low2float(vB[pi].a);
                    ay  += wb[pi] * __high2float(vB[pi].a);
                    az  += wb[pi] * __low2float(vB[pi].b);
                    aw4 += wb[pi] * __high2float(vB[pi].b);
                }
            }
            ax  += __shfl_xor(ax, 32, 64);
            ay  += __shfl_xor(ay, 32, 64);
            az  += __shfl_xor(az, 32, 64);
            aw4 += __shfl_xor(aw4, 32, 64);
            if (half == 0)
                og[(size_t)(r0 + q) * 32 + cl] = make_float4(ax, ay, az, aw4);
        }
    }
}

// ---- gather, fp32 fallback (ws too small) ----
__global__ __launch_bounds__(256, 4) void msda_gather_f32_kernel(
    const float* __restrict__ query,
    const float* __restrict__ value,
    const float* __restrict__ qloc,
    const float* __restrict__ Woff,
    const float* __restrict__ boff,
    const float* __restrict__ Wattn,
    const float* __restrict__ battn,
    float* __restrict__ acc_out)
{
    __shared__ __align__(16) char smem_u[QB * 128 * 4];   // 16 KB: q_tile / tab
    MSDA_PROLOGUE

    {
        const int wv   = tid >> 6;
        const int lane = tid & 63;
        const int half = lane >> 5;
        const int cl   = lane & 31;
        const float4* vb = (const float4*)value
                         + (size_t)(blockIdx.x >> 10) * (40960 * 32);
        float4* og = (float4*)acc_out;

        #pragma unroll 1
        for (int i = 0; i < 8; ++i) {
            const int q = wv * 8 + i;
            float ax = 0.f, ay = 0.f, az = 0.f, aw4 = 0.f;

            #pragma unroll 1
            for (int p0 = 0; p0 < 16; p0 += 8) {
                float wa[8], wb[8];
                int   oa[8], ob[8];
                #pragma unroll
                for (int pi = 0; pi < 8; ++pi) {
                    const int4 t = tab[((q * 16 + p0 + pi) << 1) + half];
                    wa[pi] = __int_as_float(t.x);
                    wb[pi] = __int_as_float(t.y);
                    oa[pi] = t.z + cl;
                    ob[pi] = t.w + cl;
                }
                float4 vA[8], vB[8];
                #pragma unroll
                for (int pi = 0; pi < 8; ++pi) {
                    vA[pi] = vb[oa[pi]];
                    vB[pi] = vb[ob[pi]];
                }
                #pragma unroll
                for (int pi = 0; pi < 8; ++pi) {
                    ax  += wa[pi] * vA[pi].x + wb[pi] * vB[pi].x;
                    ay  += wa[pi] * vA[pi].y + wb[pi] * vB[pi].y;
                    az  += wa[pi] * vA[pi].z + wb[pi] * vB[pi].z;
                    aw4 += wa[pi] * vA[pi].w + wb[pi] * vB[pi].w;
                }
            }
            ax  += __shfl_xor(ax, 32, 64);
            ay  += __shfl_xor(ay, 32, 64);
            az  += __shfl_xor(az, 32, 64);
            aw4 += __shfl_xor(aw4, 32, 64);
            if (half == 0)
                og[(size_t)(r0 + q) * 32 + cl] = make_float4(ax, ay, az, aw4);
        }
    }
}

// ---- MFMA fp16 output GEMM: out[128r x 128c] = acc @ Wout + bout, in-place ----
// A tile: acc rows cvt fp32->fp16, LDS [m][k] pad 136 (row stride 272 B: b128-
// aligned, 2-way bank alias = free). B tile: wTg (Wout^T fp16) coalesced copy,
// LDS [n][k] pad 136. mfma_f32_16x16x32_f16; C/D: col=lane&15, row=quad*4+reg.
__global__ __launch_bounds__(256, 2) void msda_out_gemm_mfma_kernel(
    const _Float16* __restrict__ wTg,
    const float* __restrict__ bout,
    float* __restrict__ out)
{
    __shared__ _Float16 aT[128 * 136];   // 34.0 KB
    __shared__ _Float16 wT[128 * 136];   // 34.0 KB
    const int tid = threadIdx.x;
    const int m0  = blockIdx.x * 128;

    // stage W^T (fp16, coalesced 16B chunks)
    #pragma unroll
    for (int i = 0; i < 8; ++i) {
        const int t  = tid + i * 256;    // 0..2047
        const int n  = t >> 4;
        const int k8 = t & 15;
        *(f16x8*)&wT[n * 136 + k8 * 8] = *(const f16x8*)&wTg[n * 128 + k8 * 8];
    }
    // stage A = acc rows (fp32 -> fp16)
    {
        const float4* src = (const float4*)out;
        #pragma unroll
        for (int i = 0; i < 16; ++i) {
            const int t  = tid + i * 256;   // 0..4095
            const int r  = t >> 5;
            const int c4 = t & 31;
            const float4 v = src[(size_t)(m0 + r) * 32 + c4];
            f16x4 h;
            h[0] = (_Float16)v.x; h[1] = (_Float16)v.y;
            h[2] = (_Float16)v.z; h[3] = (_Float16)v.w;
            *(f16x4*)&aT[r * 136 + c4 * 4] = h;
        }
    }
    __syncthreads();

    const int wv   = tid >> 6;     // wave 0..3 -> rows wv*32 .. wv*32+31
    const int lane = tid & 63;
    const int quad = lane >> 4;
    const int lr   = lane & 15;

    f32x4 acc_[2][8];
    #pragma unroll
    for (int mt = 0; mt < 2; ++mt)
        #pragma unroll
        for (int nt = 0; nt < 8; ++nt)
            acc_[mt][nt] = (f32x4){0.f, 0.f, 0.f, 0.f};

    #pragma unroll
    for (int k0 = 0; k0 < 128; k0 += 32) {
        const f16x8 a0 = *(const f16x8*)&aT[(wv * 32 +  0 + lr) * 136 + k0 + quad * 8];
        const f16x8 a1 = *(const f16x8*)&aT[(wv * 32 + 16 + lr) * 136 + k0 + quad * 8];
        #pragma unroll
        for (int nt = 0; nt < 8; ++nt) {
            const f16x8 b = *(const f16x8*)&wT[(nt * 16 + lr) * 136 + k0 + quad * 8];
            acc_[0][nt] = __builtin_amdgcn_mfma_f32_16x16x32_f16(a0, b, acc_[0][nt], 0, 0, 0);
            acc_[1][nt] = __builtin_amdgcn_mfma_f32_16x16x32_f16(a1, b, acc_[1][nt], 0, 0, 0);
        }
    }

    #pragma unroll
    for (int nt = 0; nt < 8; ++nt) {
        const float bb = bout[nt * 16 + lr];
        #pragma unroll
        for (int mt = 0; mt < 2; ++mt) {
            #pragma unroll
            for (int reg = 0; reg < 4; ++reg) {
                const int row = m0 + wv * 32 + mt * 16 + quad * 4 + reg;
                out[(size_t)row * 128 + nt * 16 + lr] = acc_[mt][nt][reg] + bb;
            }
        }
    }
}

// ---- fp32 output GEMM fallback (R6 version) ----
#define GR 128
__global__ __launch_bounds__(256, 2) void msda_out_gemm_f32_kernel(
    const float* __restrict__ Wout,
    const float* __restrict__ bout,
    float* __restrict__ out)
{
    __shared__ __align__(16) float a_tile[GR * 68];
    __shared__ __align__(16) float w_tile[64 * 128];
    const int tid  = threadIdx.x;
    const int r0   = blockIdx.x * GR;
    const int trow = tid >> 4;
    const int tcol = tid & 15;

    float4 o[8][2];
    #pragma unroll
    for (int k = 0; k < 8; ++k) {
        o[k][0] = make_float4(0.f, 0.f, 0.f, 0.f);
        o[k][1] = make_float4(0.f, 0.f, 0.f, 0.f);
    }

    #pragma unroll 1
    for (int h = 0; h < 2; ++h) {
        {
            const float4* src = (const float4*)out;
            #pragma unroll
            for (int i = 0; i < 8; ++i) {
                const int t  = tid + i * 256;
                const int r  = t >> 4;
                const int c4 = t & 15;
                const float4 v = src[(size_t)(r0 + r) * 32 + h * 16 + c4];
                *(float4*)&a_tile[r * 68 + c4 * 4] = v;
            }
            const float4* ws = (const float4*)Wout + (size_t)h * 64 * 32;
            float4* wd = (float4*)w_tile;
            #pragma unroll
            for (int i = 0; i < 8; ++i)
                wd[tid + i * 256] = ws[tid + i * 256];
        }
        __syncthreads();

        #pragma unroll 1
        for (int c4 = 0; c4 < 16; ++c4) {
            float4 a4[8];
            #pragma unroll
            for (int k = 0; k < 8; ++k)
                a4[k] = *(const float4*)&a_tile[(trow + 16 * k) * 68 + c4 * 4];
            #pragma unroll
            for (int j = 0; j < 4; ++j) {
                const int ci = c4 * 4 + j;
                const float4 w0 = *(const float4*)&w_tile[ci * 128 + tcol * 4];
                const float4 w1 = *(const float4*)&w_tile[ci * 128 + 64 + tcol * 4];
                #pragma unroll
                for (int k = 0; k < 8; ++k) {
                    const float a = (j == 0) ? a4[k].x : (j == 1) ? a4[k].y
                                  : (j == 2) ? a4[k].z : a4[k].w;
                    o[k][0].x += a * w0.x; o[k][0].y += a * w0.y;
                    o[k][0].z += a * w0.z; o[k][0].w += a * w0.w;
                    o[k][1].x += a * w1.x; o[k][1].y += a * w1.y;
                    o[k][1].z += a * w1.z; o[k][1].w += a * w1.w;
                }
            }
        }
        __syncthreads();
    }

    const float4 b0 = ((const float4*)bout)[tcol];
    const float4 b1 = ((const float4*)bout)[16 + tcol];
    float4* og = (float4*)out;
    #pragma unroll
    for (int k = 0; k < 8; ++k) {
        const size_t row = (size_t)(r0 + trow + 16 * k);
        float4 v0 = o[k][0], v1 = o[k][1];
        v0.x += b0.x; v0.y += b0.y; v0.z += b0.z; v0.w += b0.w;
        v1.x += b1.x; v1.y += b1.y; v1.z += b1.z; v1.w += b1.w;
        og[row * 32 + tcol]      = v0;
        og[row * 32 + 16 + tcol] = v1;
    }
}

extern "C" void kernel_launch(void* const* d_in, const int* in_sizes, int n_in,
                              void* d_out, int out_size, void* d_ws, size_t ws_size,
                              hipStream_t stream) {
    const float* query = (const float*)d_in[0];
    const float* value = (const float*)d_in[1];
    const float* qloc  = (const float*)d_in[2];
    const float* Woff  = (const float*)d_in[5];
    const float* boff  = (const float*)d_in[6];
    const float* Wattn = (const float*)d_in[7];
    const float* battn = (const float*)d_in[8];
    const float* Wout  = (const float*)d_in[9];
    const float* bout  = (const float*)d_in[10];
    float* out = (float*)d_out;

    const int n_val = 2 * 40960 * 128;                 // 10,485,760 floats
    const size_t f16_bytes = (size_t)n_val * 2;        // 20,971,520 B
    const size_t wT_bytes  = 128 * 128 * 2;            // 32,768 B

    if (ws_size >= f16_bytes + wT_bytes) {
        h2x2* val16 = (h2x2*)d_ws;
        _Float16* wTg = (_Float16*)((char*)d_ws + f16_bytes);
        const int n4 = n_val / 4;
        hipLaunchKernelGGL(cvt_value_f16_kernel, dim3((n4 + 255) / 256), dim3(256),
                           0, stream, (const float4*)value, val16, n4);
        hipLaunchKernelGGL(wout_transpose_kernel, dim3(1), dim3(256), 0, stream,
                           Wout, wTg);
        hipLaunchKernelGGL(msda_gather_f16_kernel, dim3(65536 / QB), dim3(256),
                           0, stream,
                           query, (const h2x2*)val16, qloc, Woff, boff, Wattn, battn, out);
        hipLaunchKernelGGL(msda_out_gemm_mfma_kernel, dim3(65536 / 128), dim3(256),
                           0, stream, (const _Float16*)wTg, bout, out);
    } else if (ws_size >= f16_bytes) {
        h2x2* val16 = (h2x2*)d_ws;
        const int n4 = n_val / 4;
        hipLaunchKernelGGL(cvt_value_f16_kernel, dim3((n4 + 255) / 256), dim3(256),
                           0, stream, (const float4*)value, val16, n4);
        hipLaunchKernelGGL(msda_gather_f16_kernel, dim3(65536 / QB), dim3(256),
                           0, stream,
                           query, (const h2x2*)val16, qloc, Woff, boff, Wattn, battn, out);
        hipLaunchKernelGGL(msda_out_gemm_f32_kernel, dim3(65536 / GR), dim3(256),
                           0, stream, Wout, bout, out);
    } else {
        hipLaunchKernelGGL(msda_gather_f32_kernel, dim3(65536 / QB), dim3(256),
                           0, stream,
                           query, value, qloc, Woff, boff, Wattn, battn, out);
        hipLaunchKernelGGL(msda_out_gemm_f32_kernel, dim3(65536 / GR), dim3(256),
                           0, stream, Wout, bout, out);
    }
}

// Round 3
// 229.308 us; speedup vs baseline: 1.1349x; 1.1349x over previous
//
#include <hip/hip_runtime.h>
#include <hip/hip_fp16.h>

// Multi-Scale Deformable Attention:
//   cvt value fp32->fp16 (d_ws) + Wout^T fp16 (ws tail) -> gather (fp16)
//   -> MFMA fp16 output GEMM (in-place on d_out)
// BS=2, NQ=32768, C=128, NH=1, NL=2, NP=8, NV=40960
// level0 = 128x256 (start 0), level1 = 64x128 (start 32768)

#define QB 32  // queries per block (gather kernel)

struct __align__(8) h2x2 { __half2 a, b; };   // 4 fp16 channels (8 B)

typedef _Float16 f16x8 __attribute__((ext_vector_type(8)));
typedef _Float16 f16x4 __attribute__((ext_vector_type(4)));
typedef float    f32x4 __attribute__((ext_vector_type(4)));

// ---- value fp32 -> fp16 conversion ----
__global__ __launch_bounds__(256) void cvt_value_f16_kernel(
    const float4* __restrict__ in, h2x2* __restrict__ out, int n4)
{
    const int i = blockIdx.x * 256 + threadIdx.x;
    if (i < n4) {
        const float4 f = in[i];
        h2x2 h;
        h.a = __floats2half2_rn(f.x, f.y);
        h.b = __floats2half2_rn(f.z, f.w);
        out[i] = h;
    }
}

// ---- Wout (fp32 [k][n]) -> wTg (fp16 [n][k]) one-block transpose ----
__global__ __launch_bounds__(256) void wout_transpose_kernel(
    const float* __restrict__ Wout, _Float16* __restrict__ wTg)
{
    __shared__ float t[128 * 129];
    const int tid = threadIdx.x;
    #pragma unroll
    for (int i = 0; i < 16; ++i) {
        const int f  = tid + i * 256;     // 0..4095 float4s
        const int k  = f >> 5;
        const int c4 = f & 31;
        const float4 v = ((const float4*)Wout)[k * 32 + c4];
        t[k * 129 + c4 * 4 + 0] = v.x;
        t[k * 129 + c4 * 4 + 1] = v.y;
        t[k * 129 + c4 * 4 + 2] = v.z;
        t[k * 129 + c4 * 4 + 3] = v.w;
    }
    __syncthreads();
    #pragma unroll
    for (int i = 0; i < 64; ++i) {
        const int f = tid + i * 256;      // 0..16383
        const int n = f >> 7;
        const int k = f & 127;
        wTg[n * 128 + k] = (_Float16)t[k * 129 + n];
    }
}

// ---------- shared prologue --------------------------------------------------
// Round-0 structure with one surgical change: the aws LDS buffer (2 KB) and the
// serial 32-thread softmax are replaced by a register softmax. Phase 3 pairs
// queries as (q, q+16) so its 16-lane groups match the table-build layout
// (e = tid -> q = tid>>4, p = tid&15; e = tid+256 -> q+16). Phase 2 (coords)
// and the table-build body are IDENTICAL to round 0.
// LDS = 16384 (q_tile/tab) + 4096 (coords) = 20480 B; 8 x 20480 = 160 KiB
// exactly -> 8 blocks/CU, one dispatch round (was 7 + straggler at 22.5 KB).
#define MSDA_PROLOGUE                                                          \
    float* q_tile = (float*)smem_u;                                            \
    int4*  tab    = (int4*)smem_u;                                             \
    const int tid = threadIdx.x;                                               \
    const int r0  = blockIdx.x * QB;                                           \
    {                                                                          \
        const float4* src = (const float4*)query + (size_t)r0 * 32;            \
        float4* dst = (float4*)q_tile;                                         \
        _Pragma("unroll")                                                      \
        for (int i = 0; i < 4; ++i)                                            \
            dst[tid + i * 256] = src[tid + i * 256];                           \
    }                                                                          \
    __syncthreads();                                                           \
    {                                                                          \
        const int jo = tid & 31;                                               \
        const int qb = (tid >> 5) * 4;                                         \
        float s[4] = {0.f, 0.f, 0.f, 0.f};                                     \
        for (int c4 = 0; c4 < 32; ++c4) {                                      \
            const float w0 = Woff[(c4 * 4 + 0) * 32 + jo];                     \
            const float w1 = Woff[(c4 * 4 + 1) * 32 + jo];                     \
            const float w2 = Woff[(c4 * 4 + 2) * 32 + jo];                     \
            const float w3 = Woff[(c4 * 4 + 3) * 32 + jo];                     \
            _Pragma("unroll")                                                  \
            for (int k = 0; k < 4; ++k) {                                      \
                const float4 q4 = *(const float4*)&q_tile[(qb + k) * 128 + c4 * 4]; \
                s[k] += q4.x * w0 + q4.y * w1 + q4.z * w2 + q4.w * w3;         \
            }                                                                  \
        }                                                                      \
        const int l = jo >> 4;                                                 \
        const int d = jo & 1;                                                  \
        const float scale = (d == 0) ? (l == 0 ? 256.f : 128.f)                \
                                     : (l == 0 ? 128.f : 64.f);                \
        const float bo = boff[jo];                                             \
        _Pragma("unroll")                                                      \
        for (int k = 0; k < 4; ++k) {                                          \
            const int row = r0 + qb + k;                                       \
            const float ql = qloc[row * 4 + l * 2 + d];                        \
            coords[(qb + k) * 32 + jo] = ql * scale + (s[k] + bo) - 0.5f;      \
        }                                                                      \
    }                                                                          \
    float wgt_[2];                                                             \
    {                                                                          \
        const int ja = tid & 15;                                               \
        const int qg = tid >> 4;             /* queries qg, qg+16 */           \
        float s[2] = {0.f, 0.f};                                               \
        for (int c4 = 0; c4 < 32; ++c4) {                                      \
            const float w0 = Wattn[(c4 * 4 + 0) * 16 + ja];                    \
            const float w1 = Wattn[(c4 * 4 + 1) * 16 + ja];                    \
            const float w2 = Wattn[(c4 * 4 + 2) * 16 + ja];                    \
            const float w3 = Wattn[(c4 * 4 + 3) * 16 + ja];                    \
            _Pragma("unroll")                                                  \
            for (int k = 0; k < 2; ++k) {                                      \
                const float4 q4 = *(const float4*)&q_tile[(qg + 16 * k) * 128 + c4 * 4]; \
                s[k] += q4.x * w0 + q4.y * w1 + q4.z * w2 + q4.w * w3;         \
            }                                                                  \
        }                                                                      \
        const float ba = battn[ja];                                            \
        float lg0 = s[0] + ba, lg1 = s[1] + ba;                                \
        float m0 = lg0, m1 = lg1;                                              \
        _Pragma("unroll")                                                      \
        for (int s_ = 1; s_ < 16; s_ <<= 1) {                                  \
            m0 = fmaxf(m0, __shfl_xor(m0, s_, 64));                            \
            m1 = fmaxf(m1, __shfl_xor(m1, s_, 64));                            \
        }                                                                      \
        const float ex0 = __expf(lg0 - m0), ex1 = __expf(lg1 - m1);            \
        float sm0 = ex0, sm1 = ex1;                                            \
        _Pragma("unroll")                                                      \
        for (int s_ = 1; s_ < 16; s_ <<= 1) {                                  \
            sm0 += __shfl_xor(sm0, s_, 64);                                    \
            sm1 += __shfl_xor(sm1, s_, 64);                                    \
        }                                                                      \
        wgt_[0] = ex0 / sm0;                                                   \
        wgt_[1] = ex1 / sm1;                                                   \
    }                                                                          \
    __syncthreads();   /* q_tile reads done; coords visible; tab may overwrite */ \
    _Pragma("unroll")                                                          \
    for (int k = 0; k < 2; ++k) {                                              \
        const int q = (tid >> 4) + 16 * k;                                     \
        const int p = tid & 15;                                                \
        const int l = p >> 3;                                                  \
        const int H = l ? 64 : 128;                                            \
        const int W = l ? 128 : 256;                                           \
        const int S = l ? 32768 : 0;                                           \
        const float x   = coords[q * 32 + p * 2 + 0];                          \
        const float y   = coords[q * 32 + p * 2 + 1];                          \
        const float wgt = wgt_[k];                                             \
        const float xf = floorf(x), yf = floorf(y);                            \
        const float lx = x - xf, ly = y - yf;                                  \
        const int x0 = (int)xf, y0 = (int)yf;                                  \
        const int x1 = x0 + 1, y1 = y0 + 1;                                    \
        const float hx = 1.f - lx, hy = 1.f - ly;                              \
        float w00 = wgt * hx * hy;                                             \
        float w10 = wgt * lx * hy;                                             \
        float w01 = wgt * hx * ly;                                             \
        float w11 = wgt * lx * ly;                                             \
        if (x0 < 0 || x0 >= W) { w00 = 0.f; w01 = 0.f; }                       \
        if (x1 < 0 || x1 >= W) { w10 = 0.f; w11 = 0.f; }                       \
        if (y0 < 0 || y0 >= H) { w00 = 0.f; w10 = 0.f; }                       \
        if (y1 < 0 || y1 >= H) { w01 = 0.f; w11 = 0.f; }                       \
        const int cx0 = min(max(x0, 0), W - 1);                                \
        const int cx1 = min(max(x1, 0), W - 1);                                \
        const int cy0 = min(max(y0, 0), H - 1);                                \
        const int cy1 = min(max(y1, 0), H - 1);                                \
        int4 e0, e1;                                                           \
        e0.x = __float_as_int(w00); e0.y = __float_as_int(w01);                \
        e0.z = (S + cy0 * W + cx0) * 32; e0.w = (S + cy1 * W + cx0) * 32;      \
        e1.x = __float_as_int(w10); e1.y = __float_as_int(w11);                \
        e1.z = (S + cy0 * W + cx1) * 32; e1.w = (S + cy1 * W + cx1) * 32;      \
        const int e_ = q * 16 + p;                                             \
        tab[e_ * 2]     = e0;                                                  \
        tab[e_ * 2 + 1] = e1;                                                  \
    }                                                                          \
    __syncthreads();

// ---- gather, fp16 value path ----
// sched_barrier(0) after the load-issue loop pins the 16-load batch: the
// scheduler may not interleave load->use pairs, so all 16 results are
// simultaneously live and MLP survives prologue-induced regalloc changes
// (rounds 1-2: prologue edits collapsed VGPR 48->32/36, dur 106->128/140 us).
__global__ __launch_bounds__(256, 4) void msda_gather_f16_kernel(
    const float* __restrict__ query,
    const h2x2*  __restrict__ value_h,
    const float* __restrict__ qloc,
    const float* __restrict__ Woff,
    const float* __restrict__ boff,
    const float* __restrict__ Wattn,
    const float* __restrict__ battn,
    float* __restrict__ acc_out)
{
    __shared__ __align__(16) char smem_u[QB * 128 * 4];   // 16 KB: q_tile / tab
    __shared__ float coords[QB * 32];                     //  4 KB
    MSDA_PROLOGUE

    {
        const int wv   = tid >> 6;
        const int lane = tid & 63;
        const int half = lane >> 5;
        const int cl   = lane & 31;
        const h2x2* vb = value_h + (size_t)(blockIdx.x >> 10) * (40960 * 32);
        float4* og = (float4*)acc_out;

        #pragma unroll 1
        for (int i = 0; i < 8; ++i) {
            const int q = wv * 8 + i;
            float ax = 0.f, ay = 0.f, az = 0.f, aw4 = 0.f;

            #pragma unroll 1
            for (int p0 = 0; p0 < 16; p0 += 8) {
                float wa[8], wb[8];
                int   oa[8], ob[8];
                #pragma unroll
                for (int pi = 0; pi < 8; ++pi) {
                    const int4 t = tab[((q * 16 + p0 + pi) << 1) + half];
                    wa[pi] = __int_as_float(t.x);
                    wb[pi] = __int_as_float(t.y);
                    oa[pi] = t.z + cl;
                    ob[pi] = t.w + cl;
                }
                h2x2 vA[8], vB[8];
                #pragma unroll
                for (int pi = 0; pi < 8; ++pi) {
                    vA[pi] = vb[oa[pi]];
                    vB[pi] = vb[ob[pi]];
                }
                __builtin_amdgcn_sched_barrier(0);   // keep all 16 loads in flight
                #pragma unroll
                for (int pi = 0; pi < 8; ++pi) {
                    ax  += wa[pi] * __low2float(vA[pi].a);
                    ay  += wa[pi] * __high2float(vA[pi].a);
                    az  += wa[pi] * __low2float(vA[pi].b);
                    aw4 += wa[pi] * __high2float(vA[pi].b);
                    ax  += wb[pi] * __low2float(vB[pi].a);
                    ay  += wb[pi] * __high2float(vB[pi].a);
                    az  += wb[pi] * __low2float(vB[pi].b);
                    aw4 += wb[pi] * __high2float(vB[pi].b);
                }
            }
            ax  += __shfl_xor(ax, 32, 64);
            ay  += __shfl_xor(ay, 32, 64);
            az  += __shfl_xor(az, 32, 64);
            aw4 += __shfl_xor(aw4, 32, 64);
            if (half == 0)
                og[(size_t)(r0 + q) * 32 + cl] = make_float4(ax, ay, az, aw4);
        }
    }
}

// ---- gather, fp32 fallback (ws too small) ----
__global__ __launch_bounds__(256, 4) void msda_gather_f32_kernel(
    const float* __restrict__ query,
    const float* __restrict__ value,
    const float* __restrict__ qloc,
    const float* __restrict__ Woff,
    const float* __restrict__ boff,
    const float* __restrict__ Wattn,
    const float* __restrict__ battn,
    float* __restrict__ acc_out)
{
    __shared__ __align__(16) char smem_u[QB * 128 * 4];   // 16 KB: q_tile / tab
    __shared__ float coords[QB * 32];                     //  4 KB
    MSDA_PROLOGUE

    {
        const int wv   = tid >> 6;
        const int lane = tid & 63;
        const int half = lane >> 5;
        const int cl   = lane & 31;
        const float4* vb = (const float4*)value
                         + (size_t)(blockIdx.x >> 10) * (40960 * 32);
        float4* og = (float4*)acc_out;

        #pragma unroll 1
        for (int i = 0; i < 8; ++i) {
            const int q = wv * 8 + i;
            float ax = 0.f, ay = 0.f, az = 0.f, aw4 = 0.f;

            #pragma unroll 1
            for (int p0 = 0; p0 < 16; p0 += 8) {
                float wa[8], wb[8];
                int   oa[8], ob[8];
                #pragma unroll
                for (int pi = 0; pi < 8; ++pi) {
                    const int4 t = tab[((q * 16 + p0 + pi) << 1) + half];
                    wa[pi] = __int_as_float(t.x);
                    wb[pi] = __int_as_float(t.y);
                    oa[pi] = t.z + cl;
                    ob[pi] = t.w + cl;
                }
                float4 vA[8], vB[8];
                #pragma unroll
                for (int pi = 0; pi < 8; ++pi) {
                    vA[pi] = vb[oa[pi]];
                    vB[pi] = vb[ob[pi]];
                }
                __builtin_amdgcn_sched_barrier(0);   // keep all 16 loads in flight
                #pragma unroll
                for (int pi = 0; pi < 8; ++pi) {
                    ax  += wa[pi] * vA[pi].x + wb[pi] * vB[pi].x;
                    ay  += wa[pi] * vA[pi].y + wb[pi] * vB[pi].y;
                    az  += wa[pi] * vA[pi].z + wb[pi] * vB[pi].z;
                    aw4 += wa[pi] * vA[pi].w + wb[pi] * vB[pi].w;
                }
            }
            ax  += __shfl_xor(ax, 32, 64);
            ay  += __shfl_xor(ay, 32, 64);
            az  += __shfl_xor(az, 32, 64);
            aw4 += __shfl_xor(aw4, 32, 64);
            if (half == 0)
                og[(size_t)(r0 + q) * 32 + cl] = make_float4(ax, ay, az, aw4);
        }
    }
}

// ---- MFMA fp16 output GEMM: out[128r x 128c] = acc @ Wout + bout, in-place ----
// A tile: acc rows cvt fp32->fp16, LDS [m][k] pad 136 (row stride 272 B: b128-
// aligned, 2-way bank alias = free). B tile: wTg (Wout^T fp16) coalesced copy,
// LDS [n][k] pad 136. mfma_f32_16x16x32_f16; C/D: col=lane&15, row=quad*4+reg.
__global__ __launch_bounds__(256, 2) void msda_out_gemm_mfma_kernel(
    const _Float16* __restrict__ wTg,
    const float* __restrict__ bout,
    float* __restrict__ out)
{
    __shared__ _Float16 aT[128 * 136];   // 34.0 KB
    __shared__ _Float16 wT[128 * 136];   // 34.0 KB
    const int tid = threadIdx.x;
    const int m0  = blockIdx.x * 128;

    // stage W^T (fp16, coalesced 16B chunks)
    #pragma unroll
    for (int i = 0; i < 8; ++i) {
        const int t  = tid + i * 256;    // 0..2047
        const int n  = t >> 4;
        const int k8 = t & 15;
        *(f16x8*)&wT[n * 136 + k8 * 8] = *(const f16x8*)&wTg[n * 128 + k8 * 8];
    }
    // stage A = acc rows (fp32 -> fp16)
    {
        const float4* src = (const float4*)out;
        #pragma unroll
        for (int i = 0; i < 16; ++i) {
            const int t  = tid + i * 256;   // 0..4095
            const int r  = t >> 5;
            const int c4 = t & 31;
            const float4 v = src[(size_t)(m0 + r) * 32 + c4];
            f16x4 h;
            h[0] = (_Float16)v.x; h[1] = (_Float16)v.y;
            h[2] = (_Float16)v.z; h[3] = (_Float16)v.w;
            *(f16x4*)&aT[r * 136 + c4 * 4] = h;
        }
    }
    __syncthreads();

    const int wv   = tid >> 6;     // wave 0..3 -> rows wv*32 .. wv*32+31
    const int lane = tid & 63;
    const int quad = lane >> 4;
    const int lr   = lane & 15;

    f32x4 acc_[2][8];
    #pragma unroll
    for (int mt = 0; mt < 2; ++mt)
        #pragma unroll
        for (int nt = 0; nt < 8; ++nt)
            acc_[mt][nt] = (f32x4){0.f, 0.f, 0.f, 0.f};

    #pragma unroll
    for (int k0 = 0; k0 < 128; k0 += 32) {
        const f16x8 a0 = *(const f16x8*)&aT[(wv * 32 +  0 + lr) * 136 + k0 + quad * 8];
        const f16x8 a1 = *(const f16x8*)&aT[(wv * 32 + 16 + lr) * 136 + k0 + quad * 8];
        #pragma unroll
        for (int nt = 0; nt < 8; ++nt) {
            const f16x8 b = *(const f16x8*)&wT[(nt * 16 + lr) * 136 + k0 + quad * 8];
            acc_[0][nt] = __builtin_amdgcn_mfma_f32_16x16x32_f16(a0, b, acc_[0][nt], 0, 0, 0);
            acc_[1][nt] = __builtin_amdgcn_mfma_f32_16x16x32_f16(a1, b, acc_[1][nt], 0, 0, 0);
        }
    }

    #pragma unroll
    for (int nt = 0; nt < 8; ++nt) {
        const float bb = bout[nt * 16 + lr];
        #pragma unroll
        for (int mt = 0; mt < 2; ++mt) {
            #pragma unroll
            for (int reg = 0; reg < 4; ++reg) {
                const int row = m0 + wv * 32 + mt * 16 + quad * 4 + reg;
                out[(size_t)row * 128 + nt * 16 + lr] = acc_[mt][nt][reg] + bb;
            }
        }
    }
}

// ---- fp32 output GEMM fallback (R6 version) ----
#define GR 128
__global__ __launch_bounds__(256, 2) void msda_out_gemm_f32_kernel(
    const float* __restrict__ Wout,
    const float* __restrict__ bout,
    float* __restrict__ out)
{
    __shared__ __align__(16) float a_tile[GR * 68];
    __shared__ __align__(16) float w_tile[64 * 128];
    const int tid  = threadIdx.x;
    const int r0   = blockIdx.x * GR;
    const int trow = tid >> 4;
    const int tcol = tid & 15;

    float4 o[8][2];
    #pragma unroll
    for (int k = 0; k < 8; ++k) {
        o[k][0] = make_float4(0.f, 0.f, 0.f, 0.f);
        o[k][1] = make_float4(0.f, 0.f, 0.f, 0.f);
    }

    #pragma unroll 1
    for (int h = 0; h < 2; ++h) {
        {
            const float4* src = (const float4*)out;
            #pragma unroll
            for (int i = 0; i < 8; ++i) {
                const int t  = tid + i * 256;
                const int r  = t >> 4;
                const int c4 = t & 15;
                const float4 v = src[(size_t)(r0 + r) * 32 + h * 16 + c4];
                *(float4*)&a_tile[r * 68 + c4 * 4] = v;
            }
            const float4* ws = (const float4*)Wout + (size_t)h * 64 * 32;
            float4* wd = (float4*)w_tile;
            #pragma unroll
            for (int i = 0; i < 8; ++i)
                wd[tid + i * 256] = ws[tid + i * 256];
        }
        __syncthreads();

        #pragma unroll 1
        for (int c4 = 0; c4 < 16; ++c4) {
            float4 a4[8];
            #pragma unroll
            for (int k = 0; k < 8; ++k)
                a4[k] = *(const float4*)&a_tile[(trow + 16 * k) * 68 + c4 * 4];
            #pragma unroll
            for (int j = 0; j < 4; ++j) {
                const int ci = c4 * 4 + j;
                const float4 w0 = *(const float4*)&w_tile[ci * 128 + tcol * 4];
                const float4 w1 = *(const float4*)&w_tile[ci * 128 + 64 + tcol * 4];
                #pragma unroll
                for (int k = 0; k < 8; ++k) {
                    const float a = (j == 0) ? a4[k].x : (j == 1) ? a4[k].y
                                  : (j == 2) ? a4[k].z : a4[k].w;
                    o[k][0].x += a * w0.x; o[k][0].y += a * w0.y;
                    o[k][0].z += a * w0.z; o[k][0].w += a * w0.w;
                    o[k][1].x += a * w1.x; o[k][1].y += a * w1.y;
                    o[k][1].z += a * w1.z; o[k][1].w += a * w1.w;
                }
            }
        }
        __syncthreads();
    }

    const float4 b0 = ((const float4*)bout)[tcol];
    const float4 b1 = ((const float4*)bout)[16 + tcol];
    float4* og = (float4*)out;
    #pragma unroll
    for (int k = 0; k < 8; ++k) {
        const size_t row = (size_t)(r0 + trow + 16 * k);
        float4 v0 = o[k][0], v1 = o[k][1];
        v0.x += b0.x; v0.y += b0.y; v0.z += b0.z; v0.w += b0.w;
        v1.x += b1.x; v1.y += b1.y; v1.z += b1.z; v1.w += b1.w;
        og[row * 32 + tcol]      = v0;
        og[row * 32 + 16 + tcol] = v1;
    }
}

extern "C" void kernel_launch(void* const* d_in, const int* in_sizes, int n_in,
                              void* d_out, int out_size, void* d_ws, size_t ws_size,
                              hipStream_t stream) {
    const float* query = (const float*)d_in[0];
    const float* value = (const float*)d_in[1];
    const float* qloc  = (const float*)d_in[2];
    const float* Woff  = (const float*)d_in[5];
    const float* boff  = (const float*)d_in[6];
    const float* Wattn = (const float*)d_in[7];
    const float* battn = (const float*)d_in[8];
    const float* Wout  = (const float*)d_in[9];
    const float* bout  = (const float*)d_in[10];
    float* out = (float*)d_out;

    const int n_val = 2 * 40960 * 128;                 // 10,485,760 floats
    const size_t f16_bytes = (size_t)n_val * 2;        // 20,971,520 B
    const size_t wT_bytes  = 128 * 128 * 2;            // 32,768 B

    if (ws_size >= f16_bytes + wT_bytes) {
        h2x2* val16 = (h2x2*)d_ws;
        _Float16* wTg = (_Float16*)((char*)d_ws + f16_bytes);
        const int n4 = n_val / 4;
        hipLaunchKernelGGL(cvt_value_f16_kernel, dim3((n4 + 255) / 256), dim3(256),
                           0, stream, (const float4*)value, val16, n4);
        hipLaunchKernelGGL(wout_transpose_kernel, dim3(1), dim3(256), 0, stream,
                           Wout, wTg);
        hipLaunchKernelGGL(msda_gather_f16_kernel, dim3(65536 / QB), dim3(256),
                           0, stream,
                           query, (const h2x2*)val16, qloc, Woff, boff, Wattn, battn, out);
        hipLaunchKernelGGL(msda_out_gemm_mfma_kernel, dim3(65536 / 128), dim3(256),
                           0, stream, (const _Float16*)wTg, bout, out);
    } else if (ws_size >= f16_bytes) {
        h2x2* val16 = (h2x2*)d_ws;
        const int n4 = n_val / 4;
        hipLaunchKernelGGL(cvt_value_f16_kernel, dim3((n4 + 255) / 256), dim3(256),
                           0, stream, (const float4*)value, val16, n4);
        hipLaunchKernelGGL(msda_gather_f16_kernel, dim3(65536 / QB), dim3(256),
                           0, stream,
                           query, (const h2x2*)val16, qloc, Woff, boff, Wattn, battn, out);
        hipLaunchKernelGGL(msda_out_gemm_f32_kernel, dim3(65536 / GR), dim3(256),
                           0, stream, Wout, bout, out);
    } else {
        hipLaunchKernelGGL(msda_gather_f32_kernel, dim3(65536 / QB), dim3(256),
                           0, stream,
                           query, value, qloc, Woff, boff, Wattn, battn, out);
        hipLaunchKernelGGL(msda_out_gemm_f32_kernel, dim3(65536 / GR), dim3(256),
                           0, stream, Wout, bout, out);
    }
}